// Round 1
// baseline (201.788 us; speedup 1.0000x reference)
//
#include <hip/hip_runtime.h>
#include <hip/hip_bf16.h>

typedef __attribute__((ext_vector_type(8))) short short8;
typedef __attribute__((ext_vector_type(4))) float f32x4;

#define LEAK 0.01f

__device__ __forceinline__ f32x4 mfma16(short8 a, short8 b, f32x4 c) {
    return __builtin_amdgcn_mfma_f32_16x16x32_bf16(a, b, c, 0, 0, 0);
}

// ---------------- prep: fp32 -> bf16, mask w0 diag, pad w2 to [128][16][64] ----
__global__ __launch_bounds__(256) void prep_kernel(
    const float* __restrict__ x,  const float* __restrict__ w0,
    const float* __restrict__ w1, const float* __restrict__ w2,
    __hip_bfloat16* __restrict__ xb,  __hip_bfloat16* __restrict__ w0b,
    __hip_bfloat16* __restrict__ w1b, __hip_bfloat16* __restrict__ w2b)
{
    int idx = blockIdx.x * 256 + threadIdx.x;   // vec4 index, grid sized exactly
    f32x4 v;
    __hip_bfloat16* dst;
    if (idx < 262144) {                         // x: [8192][128]
        v = reinterpret_cast<const f32x4*>(x)[idx];
        dst = xb + (idx << 2);
    } else if (idx < 524288) {                  // w0 masked: [128][64][128]
        int e = idx - 262144;
        v = reinterpret_cast<const f32x4*>(w0)[e];
        int base = e << 2;
        int t = base >> 13;                     // 64*128 elements per t
        int j = base & 127;
        #pragma unroll
        for (int c = 0; c < 4; ++c) if (j + c == t) v[c] = 0.f;
        dst = w0b + base;
    } else if (idx < 655360) {                  // w1: [128][64][64]
        int e = idx - 524288;
        v = reinterpret_cast<const f32x4*>(w1)[e];
        dst = w1b + (e << 2);
    } else {                                    // w2 padded: [128][16][64]
        int e = idx - 655360;                   // < 32768
        int base = e << 2;
        int t = base >> 10;
        int rem = base & 1023;
        int i = rem >> 6;
        int j = rem & 63;
        if (i < 2) v = reinterpret_cast<const f32x4*>(w2)[(t * 128 + i * 64 + j) >> 2];
        else       v = f32x4{0.f, 0.f, 0.f, 0.f};
        dst = w2b + base;
    }
    __hip_bfloat162* d2 = reinterpret_cast<__hip_bfloat162*>(dst);
    d2[0] = __float22bfloat162_rn(make_float2(v[0], v[1]));
    d2[1] = __float22bfloat162_rn(make_float2(v[2], v[3]));
}

// ---------------- main fused MLP ----------------
// grid: 8192 blocks of 256 threads. block -> (t, 128 batch rows). wave -> 32 rows.
__global__ __launch_bounds__(256) void mlp_kernel(
    const __hip_bfloat16* __restrict__ xb,
    const __hip_bfloat16* __restrict__ w0b,
    const __hip_bfloat16* __restrict__ w1b,
    const __hip_bfloat16* __restrict__ w2b,
    const float* __restrict__ b0, const float* __restrict__ b1,
    const float* __restrict__ b2, float* __restrict__ out)
{
    // wave-private activation tiles: 32 rows x 64 cols bf16, XOR-swizzled rows
    __shared__ __align__(16) char Hs [4][4096];
    __shared__ __align__(16) char H2s[4][4096];

    const int tid  = threadIdx.x;
    const int wave = tid >> 6;
    const int lane = tid & 63;
    const int g    = lane >> 4;       // 0..3
    const int r16  = lane & 15;       // 0..15

    const int bid = blockIdx.x;
    const int mc  = bid >> 7;                       // batch chunk (64)
    const int jj  = bid & 127;
    const int t   = ((jj & 7) << 4) | (jj >> 3);    // XCD k gets t in [16k,16k+16)
    const int mbase = mc * 128 + wave * 32;         // this wave's first batch row

    char* myH  = Hs[wave];
    char* myH2 = H2s[wave];

    // ---- B0 fragments: B[k][n] = w0'[n][k], lane: n = nt*16+r16, k = kk*32+g*8 ----
    const __hip_bfloat16* w0t = w0b + t * (64 * 128);
    short8 bf0[4][4];
    #pragma unroll
    for (int nt = 0; nt < 4; ++nt)
        #pragma unroll
        for (int kk = 0; kk < 4; ++kk)
            bf0[nt][kk] = *reinterpret_cast<const short8*>(w0t + (nt*16 + r16)*128 + kk*32 + g*8);

    // ---- layer 0: H = X @ W0'^T  (M=32/wave, N=64, K=128) ----
    f32x4 acc0[2][4];
    #pragma unroll
    for (int mt = 0; mt < 2; ++mt)
        #pragma unroll
        for (int nt = 0; nt < 4; ++nt)
            acc0[mt][nt] = f32x4{0.f, 0.f, 0.f, 0.f};

    #pragma unroll
    for (int mt = 0; mt < 2; ++mt) {
        const __hip_bfloat16* xrow = xb + (mbase + mt*16 + r16) * 128 + g*8;
        short8 a[4];
        #pragma unroll
        for (int kk = 0; kk < 4; ++kk)
            a[kk] = *reinterpret_cast<const short8*>(xrow + kk*32);
        #pragma unroll
        for (int nt = 0; nt < 4; ++nt)
            #pragma unroll
            for (int kk = 0; kk < 4; ++kk)
                acc0[mt][nt] = mfma16(a[kk], bf0[nt][kk], acc0[mt][nt]);
    }

    // ---- epilogue 0: bias + leaky -> LDS (swizzled bf16) ----
    const float* b0t = b0 + t * 64;
    #pragma unroll
    for (int nt = 0; nt < 4; ++nt) {
        const float bias = b0t[nt*16 + r16];
        const int colb = (nt*16 + r16) * 2;
        #pragma unroll
        for (int mt = 0; mt < 2; ++mt)
            #pragma unroll
            for (int rg = 0; rg < 4; ++rg) {
                float v = acc0[mt][nt][rg] + bias;
                v = fmaxf(v, LEAK * v);
                int row = mt*16 + 4*g + rg;
                *reinterpret_cast<__hip_bfloat16*>(myH + row*128 + (colb ^ ((row & 7) << 4)))
                    = __float2bfloat16(v);
            }
    }

    // ---- layer 1: H2 = H @ W1^T  (K=64) ----
    const __hip_bfloat16* w1t = w1b + t * (64 * 64);
    short8 bf1[4][2];
    #pragma unroll
    for (int nt = 0; nt < 4; ++nt)
        #pragma unroll
        for (int kk = 0; kk < 2; ++kk)
            bf1[nt][kk] = *reinterpret_cast<const short8*>(w1t + (nt*16 + r16)*64 + kk*32 + g*8);

    f32x4 acc1[2][4];
    #pragma unroll
    for (int mt = 0; mt < 2; ++mt)
        #pragma unroll
        for (int nt = 0; nt < 4; ++nt)
            acc1[mt][nt] = f32x4{0.f, 0.f, 0.f, 0.f};

    #pragma unroll
    for (int mt = 0; mt < 2; ++mt) {
        short8 a[2];
        #pragma unroll
        for (int kk = 0; kk < 2; ++kk) {
            int row = mt*16 + r16;
            a[kk] = *reinterpret_cast<const short8*>(myH + row*128 + ((kk*64 + g*16) ^ ((row & 7) << 4)));
        }
        #pragma unroll
        for (int nt = 0; nt < 4; ++nt)
            #pragma unroll
            for (int kk = 0; kk < 2; ++kk)
                acc1[mt][nt] = mfma16(a[kk], bf1[nt][kk], acc1[mt][nt]);
    }

    // ---- epilogue 1: bias + leaky -> LDS ----
    const float* b1t = b1 + t * 64;
    #pragma unroll
    for (int nt = 0; nt < 4; ++nt) {
        const float bias = b1t[nt*16 + r16];
        const int colb = (nt*16 + r16) * 2;
        #pragma unroll
        for (int mt = 0; mt < 2; ++mt)
            #pragma unroll
            for (int rg = 0; rg < 4; ++rg) {
                float v = acc1[mt][nt][rg] + bias;
                v = fmaxf(v, LEAK * v);
                int row = mt*16 + 4*g + rg;
                *reinterpret_cast<__hip_bfloat16*>(myH2 + row*128 + (colb ^ ((row & 7) << 4)))
                    = __float2bfloat16(v);
            }
    }

    // ---- layer 2: OUT = H2 @ W2p^T  (N=16 padded, only cols 0,1 real) ----
    const __hip_bfloat16* w2t = w2b + t * (16 * 64);
    short8 bf2[2];
    #pragma unroll
    for (int kk = 0; kk < 2; ++kk)
        bf2[kk] = *reinterpret_cast<const short8*>(w2t + r16*64 + kk*32 + g*8);

    f32x4 acc2[2];
    #pragma unroll
    for (int mt = 0; mt < 2; ++mt) acc2[mt] = f32x4{0.f, 0.f, 0.f, 0.f};

    #pragma unroll
    for (int mt = 0; mt < 2; ++mt) {
        short8 a[2];
        #pragma unroll
        for (int kk = 0; kk < 2; ++kk) {
            int row = mt*16 + r16;
            a[kk] = *reinterpret_cast<const short8*>(myH2 + row*128 + ((kk*64 + g*16) ^ ((row & 7) << 4)));
        }
        #pragma unroll
        for (int kk = 0; kk < 2; ++kk)
            acc2[mt] = mfma16(a[kk], bf2[kk], acc2[mt]);
    }

    // ---- store out[b][t][p], p = r16 (<2) ----
    if (r16 < 2) {
        const float bias = b2[t*2 + r16];
        #pragma unroll
        for (int mt = 0; mt < 2; ++mt)
            #pragma unroll
            for (int rg = 0; rg < 4; ++rg) {
                int brow = mbase + mt*16 + 4*g + rg;
                out[brow*256 + t*2 + r16] = acc2[mt][rg] + bias;
            }
    }
}

extern "C" void kernel_launch(void* const* d_in, const int* in_sizes, int n_in,
                              void* d_out, int out_size, void* d_ws, size_t ws_size,
                              hipStream_t stream)
{
    const float* x  = (const float*)d_in[0];
    const float* w0 = (const float*)d_in[1];
    const float* b0 = (const float*)d_in[2];
    const float* w1 = (const float*)d_in[3];
    const float* b1 = (const float*)d_in[4];
    const float* w2 = (const float*)d_in[5];
    const float* b2 = (const float*)d_in[6];
    float* out = (float*)d_out;

    if (ws_size < (6u << 20)) return;  // need 5.25 MB of scratch

    char* ws = (char*)d_ws;
    __hip_bfloat16* xb  = (__hip_bfloat16*)(ws);
    __hip_bfloat16* w0b = (__hip_bfloat16*)(ws + (1u << 21));               // +2MB
    __hip_bfloat16* w1b = (__hip_bfloat16*)(ws + (1u << 22));               // +4MB
    __hip_bfloat16* w2b = (__hip_bfloat16*)(ws + (1u << 22) + (1u << 20));  // +5MB

    prep_kernel<<<2688, 256, 0, stream>>>(x, w0, w1, w2, xb, w0b, w1b, w2b);
    mlp_kernel<<<8192, 256, 0, stream>>>(xb, w0b, w1b, w2b, b0, b1, b2, out);
}

// Round 2
// 159.198 us; speedup vs baseline: 1.2675x; 1.2675x over previous
//
#include <hip/hip_runtime.h>
#include <hip/hip_bf16.h>

typedef __attribute__((ext_vector_type(8))) short short8;
typedef __attribute__((ext_vector_type(4))) float f32x4;

#define LEAK 0.01f

__device__ __forceinline__ f32x4 mfma16(short8 a, short8 b, f32x4 c) {
    return __builtin_amdgcn_mfma_f32_16x16x32_bf16(a, b, c, 0, 0, 0);
}

// ---------------- prep: fp32 -> bf16, mask w0 diag, pad w2 to [128][16][64] ----
__global__ __launch_bounds__(256) void prep_kernel(
    const float* __restrict__ x,  const float* __restrict__ w0,
    const float* __restrict__ w1, const float* __restrict__ w2,
    __hip_bfloat16* __restrict__ xb,  __hip_bfloat16* __restrict__ w0b,
    __hip_bfloat16* __restrict__ w1b, __hip_bfloat16* __restrict__ w2b)
{
    int idx = blockIdx.x * 256 + threadIdx.x;   // vec4 index, grid sized exactly
    f32x4 v;
    __hip_bfloat16* dst;
    if (idx < 262144) {                         // x: [8192][128]
        v = reinterpret_cast<const f32x4*>(x)[idx];
        dst = xb + (idx << 2);
    } else if (idx < 524288) {                  // w0 masked: [128][64][128]
        int e = idx - 262144;
        v = reinterpret_cast<const f32x4*>(w0)[e];
        int base = e << 2;
        int t = base >> 13;                     // 64*128 elements per t
        int j = base & 127;
        #pragma unroll
        for (int c = 0; c < 4; ++c) if (j + c == t) v[c] = 0.f;
        dst = w0b + base;
    } else if (idx < 655360) {                  // w1: [128][64][64]
        int e = idx - 524288;
        v = reinterpret_cast<const f32x4*>(w1)[e];
        dst = w1b + (e << 2);
    } else {                                    // w2 padded: [128][16][64]
        int e = idx - 655360;                   // < 32768
        int base = e << 2;
        int t = base >> 10;
        int rem = base & 1023;
        int i = rem >> 6;
        int j = rem & 63;
        if (i < 2) v = reinterpret_cast<const f32x4*>(w2)[(t * 128 + i * 64 + j) >> 2];
        else       v = f32x4{0.f, 0.f, 0.f, 0.f};
        dst = w2b + base;
    }
    __hip_bfloat162* d2 = reinterpret_cast<__hip_bfloat162*>(dst);
    d2[0] = __float22bfloat162_rn(make_float2(v[0], v[1]));
    d2[1] = __float22bfloat162_rn(make_float2(v[2], v[3]));
}

// ---------------- main fused MLP ----------------
// grid: 1024 blocks x 512 thr. block -> (t, 1024 batch rows). wave -> 128 rows.
// weights staged once per block into swizzled LDS; activations in wave-private LDS tiles.
__global__ __launch_bounds__(512, 4) void mlp_kernel(
    const __hip_bfloat16* __restrict__ xb,
    const __hip_bfloat16* __restrict__ w0b,
    const __hip_bfloat16* __restrict__ w1b,
    const __hip_bfloat16* __restrict__ w2b,
    const float* __restrict__ b0, const float* __restrict__ b1,
    const float* __restrict__ b2, float* __restrict__ out)
{
    __shared__ __align__(16) char sW0[16384];   // [64][128] bf16, swizzled
    __shared__ __align__(16) char sW1[8192];    // [64][64]  bf16, swizzled
    __shared__ __align__(16) char sW2[2048];    // [16][64]  bf16, swizzled
    __shared__ __align__(16) char sH [8][2048]; // per-wave 16x64 bf16, swizzled
    __shared__ __align__(16) char sH2[8][2048];

    const int tid  = threadIdx.x;
    const int wave = tid >> 6;
    const int lane = tid & 63;
    const int g    = lane >> 4;       // 0..3
    const int r16  = lane & 15;       // 0..15

    const int bid   = blockIdx.x;                       // 0..1023
    const int t     = (bid & 7) * 16 + (bid >> 6);      // XCD k owns t in [16k,16k+16)
    const int chunk = (bid >> 3) & 7;                   // 0..7, 1024 rows each

    // ---- stage weights: coalesced 16B global loads -> swizzled LDS ----
    const short8* gw0 = reinterpret_cast<const short8*>(w0b + t * (64 * 128));
    const short8* gw1 = reinterpret_cast<const short8*>(w1b + t * (64 * 64));
    const short8* gw2 = reinterpret_cast<const short8*>(w2b + t * (16 * 64));
    #pragma unroll
    for (int it = 0; it < 2; ++it) {
        int i = tid + it * 512;                         // 1024 chunks of 16B
        int row = i >> 4, col = (i & 15) << 4;          // row bytes = 256
        *reinterpret_cast<short8*>(sW0 + row * 256 + (col ^ ((row & 7) << 4))) = gw0[i];
    }
    {
        int i = tid;                                    // 512 chunks
        int row = i >> 3, col = (i & 7) << 4;           // row bytes = 128
        *reinterpret_cast<short8*>(sW1 + row * 128 + (col ^ ((row & 7) << 4))) = gw1[i];
    }
    if (tid < 128) {
        int i = tid;                                    // 128 chunks
        int row = i >> 3, col = (i & 7) << 4;
        *reinterpret_cast<short8*>(sW2 + row * 128 + (col ^ ((row & 7) << 4))) = gw2[i];
    }

    // ---- biases to registers (overlap with staging) ----
    float b0v[4], b1v[4];
    #pragma unroll
    for (int nt = 0; nt < 4; ++nt) {
        b0v[nt] = b0[t * 64 + nt * 16 + r16];
        b1v[nt] = b1[t * 64 + nt * 16 + r16];
    }
    const float b2v = (r16 < 2) ? b2[t * 2 + r16] : 0.f;

    __syncthreads();

    const int swz = (r16 & 7) << 4;

    // ---- hoist w1/w2 B-fragments to registers ----
    short8 bf1[4][2];
    #pragma unroll
    for (int nt = 0; nt < 4; ++nt)
        #pragma unroll
        for (int kk = 0; kk < 2; ++kk)
            bf1[nt][kk] = *reinterpret_cast<const short8*>(
                sW1 + (nt * 16 + r16) * 128 + ((kk * 64 + g * 16) ^ swz));
    short8 bf2[2];
    #pragma unroll
    for (int kk = 0; kk < 2; ++kk)
        bf2[kk] = *reinterpret_cast<const short8*>(
            sW2 + r16 * 128 + ((kk * 64 + g * 16) ^ swz));

    char* myH  = sH[wave];
    char* myH2 = sH2[wave];
    const int rowbase = chunk * 1024 + wave * 128;
    const __hip_bfloat16* xr0 = xb + (rowbase + r16) * 128 + g * 8;
    float* outp = out + (rowbase + g * 4) * 256 + t * 2 + r16;   // valid when r16<2

    #pragma unroll
    for (int mt = 0; mt < 8; ++mt) {
        // ---- A-fragments: 16 rows of x (global, L2-resident) ----
        const __hip_bfloat16* xr = xr0 + mt * (16 * 128);
        short8 a[4];
        #pragma unroll
        for (int kk = 0; kk < 4; ++kk)
            a[kk] = *reinterpret_cast<const short8*>(xr + kk * 32);

        // ---- layer 0: 16 MFMA, bias folded into C-init ----
        f32x4 acc0[4];
        #pragma unroll
        for (int nt = 0; nt < 4; ++nt)
            acc0[nt] = f32x4{b0v[nt], b0v[nt], b0v[nt], b0v[nt]};
        #pragma unroll
        for (int nt = 0; nt < 4; ++nt) {
            short8 w0f[4];
            #pragma unroll
            for (int kk = 0; kk < 4; ++kk)
                w0f[kk] = *reinterpret_cast<const short8*>(
                    sW0 + (nt * 16 + r16) * 256 + ((kk * 64 + g * 16) ^ swz));
            #pragma unroll
            for (int kk = 0; kk < 4; ++kk)
                acc0[nt] = mfma16(a[kk], w0f[kk], acc0[nt]);
        }

        // ---- epilogue 0: leaky -> LDS bf16 (swizzled) ----
        #pragma unroll
        for (int nt = 0; nt < 4; ++nt) {
            const int colb = (nt * 16 + r16) * 2;
            #pragma unroll
            for (int rg = 0; rg < 4; ++rg) {
                float v = acc0[nt][rg];
                v = fmaxf(v, LEAK * v);
                int row = g * 4 + rg;
                *reinterpret_cast<__hip_bfloat16*>(myH + row * 128 + (colb ^ ((row & 7) << 4)))
                    = __float2bfloat16(v);
            }
        }

        // ---- layer 1: 8 MFMA ----
        short8 a1[2];
        #pragma unroll
        for (int kk = 0; kk < 2; ++kk)
            a1[kk] = *reinterpret_cast<const short8*>(
                myH + r16 * 128 + ((kk * 64 + g * 16) ^ swz));
        f32x4 acc1[4];
        #pragma unroll
        for (int nt = 0; nt < 4; ++nt)
            acc1[nt] = f32x4{b1v[nt], b1v[nt], b1v[nt], b1v[nt]};
        #pragma unroll
        for (int nt = 0; nt < 4; ++nt)
            #pragma unroll
            for (int kk = 0; kk < 2; ++kk)
                acc1[nt] = mfma16(a1[kk], bf1[nt][kk], acc1[nt]);

        // ---- epilogue 1 ----
        #pragma unroll
        for (int nt = 0; nt < 4; ++nt) {
            const int colb = (nt * 16 + r16) * 2;
            #pragma unroll
            for (int rg = 0; rg < 4; ++rg) {
                float v = acc1[nt][rg];
                v = fmaxf(v, LEAK * v);
                int row = g * 4 + rg;
                *reinterpret_cast<__hip_bfloat16*>(myH2 + row * 128 + (colb ^ ((row & 7) << 4)))
                    = __float2bfloat16(v);
            }
        }

        // ---- layer 2: 2 MFMA (N=16 padded, cols 0,1 real) ----
        short8 a2[2];
        #pragma unroll
        for (int kk = 0; kk < 2; ++kk)
            a2[kk] = *reinterpret_cast<const short8*>(
                myH2 + r16 * 128 + ((kk * 64 + g * 16) ^ swz));
        f32x4 acc2 = f32x4{b2v, b2v, b2v, b2v};
        #pragma unroll
        for (int kk = 0; kk < 2; ++kk)
            acc2 = mfma16(a2[kk], bf2[kk], acc2);

        // ---- store out[b][t][p], p=r16<2 ----
        if (r16 < 2) {
            #pragma unroll
            for (int rg = 0; rg < 4; ++rg)
                outp[(mt * 16 + rg) * 256] = acc2[rg];
        }
    }
}

extern "C" void kernel_launch(void* const* d_in, const int* in_sizes, int n_in,
                              void* d_out, int out_size, void* d_ws, size_t ws_size,
                              hipStream_t stream)
{
    const float* x  = (const float*)d_in[0];
    const float* w0 = (const float*)d_in[1];
    const float* b0 = (const float*)d_in[2];
    const float* w1 = (const float*)d_in[3];
    const float* b1 = (const float*)d_in[4];
    const float* w2 = (const float*)d_in[5];
    const float* b2 = (const float*)d_in[6];
    float* out = (float*)d_out;

    if (ws_size < (6u << 20)) return;  // need 5.25 MB of scratch

    char* ws = (char*)d_ws;
    __hip_bfloat16* xb  = (__hip_bfloat16*)(ws);
    __hip_bfloat16* w0b = (__hip_bfloat16*)(ws + (1u << 21));               // +2MB
    __hip_bfloat16* w1b = (__hip_bfloat16*)(ws + (1u << 22));               // +4MB
    __hip_bfloat16* w2b = (__hip_bfloat16*)(ws + (1u << 22) + (1u << 20));  // +5MB

    prep_kernel<<<2688, 256, 0, stream>>>(x, w0, w1, w2, xb, w0b, w1b, w2b);
    mlp_kernel<<<1024, 512, 0, stream>>>(xb, w0b, w1b, w2b, b0, b1, b2, out);
}

// Round 3
// 149.490 us; speedup vs baseline: 1.3498x; 1.0649x over previous
//
#include <hip/hip_runtime.h>
#include <hip/hip_bf16.h>

typedef __attribute__((ext_vector_type(8))) short short8;
typedef __attribute__((ext_vector_type(4))) float f32x4;

#define LEAK 0.01f

__device__ __forceinline__ f32x4 mfma16(short8 a, short8 b, f32x4 c) {
    return __builtin_amdgcn_mfma_f32_16x16x32_bf16(a, b, c, 0, 0, 0);
}

__device__ __forceinline__ unsigned pkbf(float a, float b) {
    __hip_bfloat162 h = __float22bfloat162_rn(make_float2(a, b));
    return *reinterpret_cast<unsigned*>(&h);
}

// In-register layer transition (no LDS): from acc[4] holding H[n=16nt+4g+r][b=r16]
// to B-frags bf[kk]: lane holds B[k=32kk+8g+e][b=r16] as bf16x8, with leaky ReLU.
// Routing among the 4 lane-groups (g = lane>>4), verified element-wise:
//   dst dword (kk, h, j) at group (x,y) = P[2kk+x][j] from group (y,h).
__device__ __forceinline__ void transition(const f32x4 acc[4], int g, short8 bf[2]) {
    unsigned P[4][2];
    #pragma unroll
    for (int nt = 0; nt < 4; ++nt)
        #pragma unroll
        for (int j = 0; j < 2; ++j) {
            float v0 = acc[nt][2*j];   v0 = fmaxf(v0, LEAK * v0);
            float v1 = acc[nt][2*j+1]; v1 = fmaxf(v1, LEAK * v1);
            P[nt][j] = pkbf(v0, v1);
        }
    const bool godd = (g & 1) != 0;
    const bool ghi  = (g >> 1) != 0;
    #pragma unroll
    for (int kk = 0; kk < 2; ++kk) {
        unsigned dw[4];
        #pragma unroll
        for (int j = 0; j < 2; ++j) {
            unsigned P0 = P[2*kk][j], P1 = P[2*kk+1][j];
            unsigned C1 = godd ? P0 : P1;
            unsigned C2 = godd ? P1 : P0;
            unsigned Y1 = __shfl_xor(C1, 16);   // from g^1
            unsigned Y2 = __shfl_xor(C1, 32);   // from g^2
            unsigned Y3 = __shfl_xor(C2, 48);   // from g^3
            unsigned lo  = godd ? Y3 : P0;      // g0:P0  g1:Y3
            unsigned hi  = godd ? Y1 : Y2;      // g2:Y2  g3:Y1
            dw[j]     = ghi ? hi : lo;
            unsigned lo2 = godd ? Y2 : Y1;      // g0:Y1  g1:Y2
            unsigned hi2 = godd ? P1 : Y3;      // g2:Y3  g3:P1
            dw[2 + j] = ghi ? hi2 : lo2;
        }
        union { unsigned u[4]; short8 s; } u;
        u.u[0] = dw[0]; u.u[1] = dw[1]; u.u[2] = dw[2]; u.u[3] = dw[3];
        bf[kk] = u.s;
    }
}

// ---------------- prep: fp32 -> bf16, mask w0 diag, pad w2 to [128][16][64] ----
__global__ __launch_bounds__(256) void prep_kernel(
    const float* __restrict__ x,  const float* __restrict__ w0,
    const float* __restrict__ w1, const float* __restrict__ w2,
    __hip_bfloat16* __restrict__ xb,  __hip_bfloat16* __restrict__ w0b,
    __hip_bfloat16* __restrict__ w1b, __hip_bfloat16* __restrict__ w2b)
{
    int idx = blockIdx.x * 256 + threadIdx.x;   // vec4 index, grid sized exactly
    f32x4 v;
    __hip_bfloat16* dst;
    if (idx < 262144) {                         // x: [8192][128]
        v = reinterpret_cast<const f32x4*>(x)[idx];
        dst = xb + (idx << 2);
    } else if (idx < 524288) {                  // w0 masked: [128][64][128]
        int e = idx - 262144;
        v = reinterpret_cast<const f32x4*>(w0)[e];
        int base = e << 2;
        int t = base >> 13;
        int j = base & 127;
        #pragma unroll
        for (int c = 0; c < 4; ++c) if (j + c == t) v[c] = 0.f;
        dst = w0b + base;
    } else if (idx < 655360) {                  // w1: [128][64][64]
        int e = idx - 524288;
        v = reinterpret_cast<const f32x4*>(w1)[e];
        dst = w1b + (e << 2);
    } else {                                    // w2 padded: [128][16][64]
        int e = idx - 655360;                   // < 32768
        int base = e << 2;
        int t = base >> 10;
        int rem = base & 1023;
        int i = rem >> 6;
        int j = rem & 63;
        if (i < 2) v = reinterpret_cast<const f32x4*>(w2)[(t * 128 + i * 64 + j) >> 2];
        else       v = f32x4{0.f, 0.f, 0.f, 0.f};
        dst = w2b + base;
    }
    __hip_bfloat162* d2 = reinterpret_cast<__hip_bfloat162*>(dst);
    d2[0] = __float22bfloat162_rn(make_float2(v[0], v[1]));
    d2[1] = __float22bfloat162_rn(make_float2(v[2], v[3]));
}

// ---------------- main fused MLP: swapped-operand MFMA, zero LDS ----------------
// grid 2048 x 256 thr. block -> (t, 512 rows); wave -> 128 rows (8 m-tiles of 16).
__global__ __launch_bounds__(256, 2) void mlp_kernel(
    const __hip_bfloat16* __restrict__ xb,
    const __hip_bfloat16* __restrict__ w0b,
    const __hip_bfloat16* __restrict__ w1b,
    const __hip_bfloat16* __restrict__ w2b,
    const float* __restrict__ b0, const float* __restrict__ b1,
    const float* __restrict__ b2, float* __restrict__ dst, int direct)
{
    const int tid  = threadIdx.x;
    const int wave = tid >> 6;
    const int lane = tid & 63;
    const int g    = lane >> 4;
    const int r16  = lane & 15;

    const int bid   = blockIdx.x;
    const int t     = (bid & 7) * 16 + ((bid >> 3) & 15);  // XCD k owns t in [16k,16k+16)
    const int chunk = bid >> 7;                            // 0..15
    const int rowbase = chunk * 512 + wave * 128;

    // ---- weight A-fragments, held in registers for the whole kernel ----
    const __hip_bfloat16* w0t = w0b + t * 8192;
    const __hip_bfloat16* w1t = w1b + t * 4096;
    const __hip_bfloat16* w2t = w2b + t * 1024;
    short8 w0f[4][4], w1f[4][2], w2f[2];
    #pragma unroll
    for (int nt = 0; nt < 4; ++nt)
        #pragma unroll
        for (int kk = 0; kk < 4; ++kk)
            w0f[nt][kk] = *reinterpret_cast<const short8*>(w0t + (nt*16 + r16)*128 + kk*32 + g*8);
    #pragma unroll
    for (int nt = 0; nt < 4; ++nt)
        #pragma unroll
        for (int kk = 0; kk < 2; ++kk)
            w1f[nt][kk] = *reinterpret_cast<const short8*>(w1t + (nt*16 + r16)*64 + kk*32 + g*8);
    #pragma unroll
    for (int kk = 0; kk < 2; ++kk)
        w2f[kk] = *reinterpret_cast<const short8*>(w2t + r16*64 + kk*32 + g*8);

    // ---- biases as C-init (row-indexed: bias[n] broadcast over batch cols) ----
    f32x4 b0v[4], b1v[4];
    #pragma unroll
    for (int nt = 0; nt < 4; ++nt) {
        b0v[nt] = *reinterpret_cast<const f32x4*>(b0 + t*64 + nt*16 + 4*g);
        b1v[nt] = *reinterpret_cast<const f32x4*>(b1 + t*64 + nt*16 + 4*g);
    }
    f32x4 acc2init = f32x4{(g == 0) ? b2[2*t] : 0.f, (g == 0) ? b2[2*t + 1] : 0.f, 0.f, 0.f};

    // ---- x B-fragments, double-buffered across m-tiles ----
    const __hip_bfloat16* xrow = xb + (rowbase + r16) * 128 + g * 8;
    short8 xf[4];
    #pragma unroll
    for (int kk = 0; kk < 4; ++kk)
        xf[kk] = *reinterpret_cast<const short8*>(xrow + kk * 32);

    #pragma unroll
    for (int mt = 0; mt < 8; ++mt) {
        short8 xn[4];
        if (mt < 7) {
            const __hip_bfloat16* xr = xrow + (mt + 1) * (16 * 128);
            #pragma unroll
            for (int kk = 0; kk < 4; ++kk)
                xn[kk] = *reinterpret_cast<const short8*>(xr + kk * 32);
        }

        // ---- layer 0: D0 = W0 . X^T  (16 MFMA), bias folded into C ----
        f32x4 acc0[4];
        #pragma unroll
        for (int nt = 0; nt < 4; ++nt) acc0[nt] = b0v[nt];
        #pragma unroll
        for (int nt = 0; nt < 4; ++nt)
            #pragma unroll
            for (int kk = 0; kk < 4; ++kk)
                acc0[nt] = mfma16(w0f[nt][kk], xf[kk], acc0[nt]);

        // ---- in-register leaky + transpose to next-layer B-frags ----
        short8 h1[2];
        transition(acc0, g, h1);

        // ---- layer 1: 8 MFMA ----
        f32x4 acc1[4];
        #pragma unroll
        for (int nt = 0; nt < 4; ++nt) acc1[nt] = b1v[nt];
        #pragma unroll
        for (int nt = 0; nt < 4; ++nt)
            #pragma unroll
            for (int kk = 0; kk < 2; ++kk)
                acc1[nt] = mfma16(w1f[nt][kk], h1[kk], acc1[nt]);

        short8 h2[2];
        transition(acc1, g, h2);

        // ---- layer 2: 2 MFMA (M=16 padded, rows 0,1 real) ----
        f32x4 acc2 = acc2init;
        #pragma unroll
        for (int kk = 0; kk < 2; ++kk)
            acc2 = mfma16(w2f[kk], h2[kk], acc2);

        // ---- store: lane g==0 holds out[p=0,1][b=r16] ----
        if (lane < 16) {
            int b = rowbase + mt * 16 + r16;
            float2 v = make_float2(acc2[0], acc2[1]);
            if (direct) *reinterpret_cast<float2*>(dst + b * 256 + t * 2) = v;       // out[b][t][p]
            else        *reinterpret_cast<float2*>(dst + t * 16384 + b * 2) = v;     // tmp[t][b][p]
        }

        #pragma unroll
        for (int kk = 0; kk < 4; ++kk) xf[kk] = xn[kk];
    }
}

// ---------------- transpose: tmp[128][8192][2] f32 -> out[8192][256] ----------------
__global__ __launch_bounds__(256) void transpose_kernel(
    const float* __restrict__ tmp, float* __restrict__ out)
{
    __shared__ float tile[32][257];
    const int b0 = blockIdx.x * 32;
    const int tid = threadIdx.x;
    #pragma unroll
    for (int it = 0; it < 16; ++it) {
        int idx = it * 256 + tid;        // 4096 float2 loads
        int tt = idx >> 5, r = idx & 31;
        float2 v = *reinterpret_cast<const float2*>(tmp + tt * 16384 + (b0 + r) * 2);
        tile[r][tt * 2]     = v.x;
        tile[r][tt * 2 + 1] = v.y;
    }
    __syncthreads();
    #pragma unroll
    for (int r = 0; r < 32; ++r)
        out[(b0 + r) * 256 + tid] = tile[r][tid];
}

extern "C" void kernel_launch(void* const* d_in, const int* in_sizes, int n_in,
                              void* d_out, int out_size, void* d_ws, size_t ws_size,
                              hipStream_t stream)
{
    const float* x  = (const float*)d_in[0];
    const float* w0 = (const float*)d_in[1];
    const float* b0 = (const float*)d_in[2];
    const float* w1 = (const float*)d_in[3];
    const float* b1 = (const float*)d_in[4];
    const float* w2 = (const float*)d_in[5];
    const float* b2 = (const float*)d_in[6];
    float* out = (float*)d_out;

    const size_t OFF_W0  = 2097152;   // xb:  8192*128*2
    const size_t OFF_W1  = 4194304;   // w0b: 128*64*128*2
    const size_t OFF_W2  = 5242880;   // w1b: 128*64*64*2
    const size_t OFF_TMP = 5505024;   // w2b: 128*16*64*2
    const size_t NEED_TMP = OFF_TMP + 8388608;  // + tmp 128*8192*2*4

    if (ws_size < OFF_TMP) return;

    char* ws = (char*)d_ws;
    __hip_bfloat16* xb  = (__hip_bfloat16*)(ws);
    __hip_bfloat16* w0b = (__hip_bfloat16*)(ws + OFF_W0);
    __hip_bfloat16* w1b = (__hip_bfloat16*)(ws + OFF_W1);
    __hip_bfloat16* w2b = (__hip_bfloat16*)(ws + OFF_W2);
    float* tmp = (float*)(ws + OFF_TMP);

    const int use_tmp = (ws_size >= NEED_TMP) ? 1 : 0;
    float* dstp = use_tmp ? tmp : out;

    prep_kernel<<<2688, 256, 0, stream>>>(x, w0, w1, w2, xb, w0b, w1b, w2b);
    mlp_kernel<<<2048, 256, 0, stream>>>(xb, w0b, w1b, w2b, b0, b1, b2, dstp, use_tmp ? 0 : 1);
    if (use_tmp)
        transpose_kernel<<<256, 256, 0, stream>>>(tmp, out);
}

// Round 5
// 129.370 us; speedup vs baseline: 1.5598x; 1.1555x over previous
//
#include <hip/hip_runtime.h>
#include <hip/hip_bf16.h>

typedef __attribute__((ext_vector_type(8))) short short8;
typedef __attribute__((ext_vector_type(16))) float f32x16;

#define LEAK 0.01f

__device__ __forceinline__ f32x16 mfma32(short8 a, short8 b, f32x16 c) {
    return __builtin_amdgcn_mfma_f32_32x32x16_bf16(a, b, c, 0, 0, 0);
}
__device__ __forceinline__ unsigned pkbf(float a, float b) {
    __hip_bfloat162 t = __float22bfloat162_rn(make_float2(a, b));
    return *reinterpret_cast<unsigned*>(&t);
}
// Half-wave swap with EXPLICIT semantics (replaces v_permlane32_swap_b32):
// after call: a = [a@h=0-lanes, b@h=0-partner] ; b = [a@h=1-partner, b@h=1-lanes]
// i.e. new_a[lane] = (h==0) ? a_own : b_from(lane-32)
//      new_b[lane] = (h==0) ? a_from(lane+32) : b_own
__device__ __forceinline__ void plswap(unsigned &a, unsigned &b, int h) {
    unsigned ax = (unsigned)__shfl_xor((int)a, 32);
    unsigned bx = (unsigned)__shfl_xor((int)b, 32);
    unsigned na = h ? bx : a;
    unsigned nb = h ? b  : ax;
    a = na; b = nb;
}

// Layer transition, fully in-register: acc (2x f32x16, D-layout rows
// (q&3)+8*(q>>2)+4h + 32nt, col=batch) -> 4 B-frags (k=16ks+8h+{0..7}),
// with leaky ReLU. pk[nt][s] = rows n0,n0+1, n0 = 32nt+8*(s>>1)+2*(s&1)+4h.
// dword d of out[ks] needs rows 16ks+8h+2d,+1  ->  s=4(ks&1)+2h+(d&1), h'=d>>1.
__device__ __forceinline__ void transition(const f32x16 &A0, const f32x16 &A1,
                                           short8 out[4], int h) {
    unsigned pk[2][8];
    #pragma unroll
    for (int nt = 0; nt < 2; ++nt) {
        const f32x16 &A = nt ? A1 : A0;
        #pragma unroll
        for (int s = 0; s < 8; ++s) {
            float u = A[2*s], v = A[2*s+1];
            u = fmaxf(u, LEAK * u); v = fmaxf(v, LEAK * v);
            pk[nt][s] = pkbf(u, v);
        }
    }
    #pragma unroll
    for (int ks = 0; ks < 4; ++ks) {
        const int nt = ks >> 1, ss = (ks & 1) * 4;
        unsigned d0 = pk[nt][ss], d1 = pk[nt][ss+1], d2 = pk[nt][ss+2], d3 = pk[nt][ss+3];
        plswap(d0, d2, h);   // d0 = dword0, d2 = dword2
        plswap(d1, d3, h);   // d1 = dword1, d3 = dword3
        union { unsigned u[4]; short8 s; } U;
        U.u[0] = d0; U.u[1] = d1; U.u[2] = d2; U.u[3] = d3;
        out[ks] = U.s;
    }
}

// ---------------- prep: bf16 + diag-mask + bias K-padding ----------------
// xp [8192][144]: k<128 = x, k==128 = 1, else 0
// w0p[128][64][144]: k<128 = w0 (j==t zeroed), k==128 = b0, else 0
// w1p[128][64][80]:  k<64 = w1, k==64 = b1, else 0
// w2p[128][32][80]:  n<2: k<64 = w2, k==64 = b2; else 0
__global__ __launch_bounds__(256) void prep_kernel(
    const float* __restrict__ x,  const float* __restrict__ w0, const float* __restrict__ b0,
    const float* __restrict__ w1, const float* __restrict__ b1,
    const float* __restrict__ w2, const float* __restrict__ b2,
    __hip_bfloat16* __restrict__ xp,  __hip_bfloat16* __restrict__ w0p,
    __hip_bfloat16* __restrict__ w1p, __hip_bfloat16* __restrict__ w2p)
{
    const int idx = blockIdx.x * 256 + threadIdx.x;
    float v[8];
    #pragma unroll
    for (int e = 0; e < 8; ++e) v[e] = 0.f;
    __hip_bfloat16* dst;

    if (idx < 147456) {                       // xp
        int b = idx / 18, ch = idx - b * 18;
        dst = xp + b * 144 + ch * 8;
        if (ch < 16) {
            const float* s = x + b * 128 + ch * 8;
            #pragma unroll
            for (int e = 0; e < 8; ++e) v[e] = s[e];
        } else if (ch == 16) v[0] = 1.f;
    } else if (idx < 294912) {                // w0p
        int i = idx - 147456;
        int r = i / 18, ch = i - r * 18;      // r = t*64+n
        int t = r >> 6;
        dst = w0p + r * 144 + ch * 8;
        if (ch < 16) {
            const float* s = w0 + r * 128 + ch * 8;
            #pragma unroll
            for (int e = 0; e < 8; ++e) v[e] = s[e];
            if ((t >> 3) == ch) v[t & 7] = 0.f;   // mask j == t
        } else if (ch == 16) v[0] = b0[r];
    } else if (idx < 376832) {                // w1p
        int i = idx - 294912;
        int r = i / 10, ch = i - r * 10;
        dst = w1p + r * 80 + ch * 8;
        if (ch < 8) {
            const float* s = w1 + r * 64 + ch * 8;
            #pragma unroll
            for (int e = 0; e < 8; ++e) v[e] = s[e];
        } else if (ch == 8) v[0] = b1[r];
    } else {                                  // w2p
        int i = idx - 376832;
        int r = i / 10, ch = i - r * 10;      // r = t*32+n
        int t = r >> 5, n = r & 31;
        dst = w2p + r * 80 + ch * 8;
        if (n < 2) {
            if (ch < 8) {
                const float* s = w2 + (t * 2 + n) * 64 + ch * 8;
                #pragma unroll
                for (int e = 0; e < 8; ++e) v[e] = s[e];
            } else if (ch == 8) v[0] = b2[t * 2 + n];
        }
    }
    union { unsigned u[4]; short8 s; } U;
    #pragma unroll
    for (int p = 0; p < 4; ++p) U.u[p] = pkbf(v[2*p], v[2*p+1]);
    *reinterpret_cast<short8*>(dst) = U.s;
}

// ---------------- main fused MLP: 32x32 MFMA + shfl transitions ----------------
// grid 1024 x 256. block -> (t, 1024 rows); wave -> 256 rows = 8 tiles of 32.
__global__ __launch_bounds__(256, 2) void mlp_kernel(
    const __hip_bfloat16* __restrict__ xp,
    const __hip_bfloat16* __restrict__ w0p,
    const __hip_bfloat16* __restrict__ w1p,
    const __hip_bfloat16* __restrict__ w2p,
    float* __restrict__ dst, int direct)
{
    const int tid  = threadIdx.x;
    const int wave = tid >> 6;
    const int lane = tid & 63;
    const int h    = lane >> 5;
    const int c    = lane & 31;

    const int bid   = blockIdx.x;
    const int t     = (bid & 7) * 16 + ((bid >> 3) & 15);  // XCD k owns t in [16k,16k+16)
    const int chunk = bid >> 7;                            // 0..7
    const int rb0   = chunk * 1024 + wave * 256;

    // ---- weight A-fragments, register-resident (A[n][k]: n=32nt+c, k=16ks+8h+e) ----
    const __hip_bfloat16* w0t = w0p + t * 9216;
    const __hip_bfloat16* w1t = w1p + t * 5120;
    const __hip_bfloat16* w2t = w2p + t * 2560;
    short8 w0f[2][9], w1f[2][5], w2f[5];
    #pragma unroll
    for (int nt = 0; nt < 2; ++nt)
        #pragma unroll
        for (int ks = 0; ks < 9; ++ks)
            w0f[nt][ks] = *reinterpret_cast<const short8*>(w0t + (nt*32 + c)*144 + ks*16 + h*8);
    #pragma unroll
    for (int nt = 0; nt < 2; ++nt)
        #pragma unroll
        for (int ks = 0; ks < 5; ++ks)
            w1f[nt][ks] = *reinterpret_cast<const short8*>(w1t + (nt*32 + c)*80 + ks*16 + h*8);
    #pragma unroll
    for (int ks = 0; ks < 5; ++ks)
        w2f[ks] = *reinterpret_cast<const short8*>(w2t + c*80 + ks*16 + h*8);

    // constant B-frag for the bias row (k=64 -> 1.0): h==0, e==0 slot
    union { unsigned u[4]; short8 s; } OneU;
    OneU.u[0] = (h == 0) ? 0x00003f80u : 0u;
    OneU.u[1] = 0u; OneU.u[2] = 0u; OneU.u[3] = 0u;
    const short8 onef = OneU.s;

    #pragma unroll 1
    for (int tile = 0; tile < 8; ++tile) {
        const int brow = rb0 + tile * 32 + c;
        const __hip_bfloat16* xr = xp + brow * 144 + h * 8;
        short8 xf[9];
        #pragma unroll
        for (int ks = 0; ks < 9; ++ks)
            xf[ks] = *reinterpret_cast<const short8*>(xr + ks * 16);

        // ---- layer 0: 18 MFMA (bias via K-pad col 128) ----
        f32x16 acc0a, acc0b;
        #pragma unroll
        for (int i = 0; i < 16; ++i) { acc0a[i] = 0.f; acc0b[i] = 0.f; }
        #pragma unroll
        for (int ks = 0; ks < 9; ++ks) acc0a = mfma32(w0f[0][ks], xf[ks], acc0a);
        #pragma unroll
        for (int ks = 0; ks < 9; ++ks) acc0b = mfma32(w0f[1][ks], xf[ks], acc0b);

        short8 h1f[4];
        transition(acc0a, acc0b, h1f, h);

        // ---- layer 1: 10 MFMA (bias row via onef) ----
        f32x16 acc1a, acc1b;
        #pragma unroll
        for (int i = 0; i < 16; ++i) { acc1a[i] = 0.f; acc1b[i] = 0.f; }
        #pragma unroll
        for (int ks = 0; ks < 4; ++ks) acc1a = mfma32(w1f[0][ks], h1f[ks], acc1a);
        acc1a = mfma32(w1f[0][4], onef, acc1a);
        #pragma unroll
        for (int ks = 0; ks < 4; ++ks) acc1b = mfma32(w1f[1][ks], h1f[ks], acc1b);
        acc1b = mfma32(w1f[1][4], onef, acc1b);

        short8 h2f[4];
        transition(acc1a, acc1b, h2f, h);

        // ---- layer 2: 5 MFMA (rows 0,1 real) ----
        f32x16 acc2;
        #pragma unroll
        for (int i = 0; i < 16; ++i) acc2[i] = 0.f;
        #pragma unroll
        for (int ks = 0; ks < 4; ++ks) acc2 = mfma32(w2f[ks], h2f[ks], acc2);
        acc2 = mfma32(w2f[4], onef, acc2);

        // ---- store: lanes h==0 hold out[p=0][b]=reg0, out[p=1][b]=reg1 ----
        if (h == 0) {
            float2 v = make_float2(acc2[0], acc2[1]);
            if (direct) *reinterpret_cast<float2*>(dst + brow * 256 + t * 2) = v;
            else        *reinterpret_cast<float2*>(dst + t * 16384 + brow * 2) = v;
        }
    }
}

// ---------------- transpose: tmp[128][8192][2] f32 -> out[8192][256] ----------------
__global__ __launch_bounds__(256) void transpose_kernel(
    const float* __restrict__ tmp, float* __restrict__ out)
{
    __shared__ float tile[32][257];
    const int b0 = blockIdx.x * 32;
    const int tid = threadIdx.x;
    #pragma unroll
    for (int it = 0; it < 16; ++it) {
        int idx = it * 256 + tid;
        int tt = idx >> 5, r = idx & 31;
        float2 v = *reinterpret_cast<const float2*>(tmp + tt * 16384 + (b0 + r) * 2);
        tile[r][tt * 2]     = v.x;
        tile[r][tt * 2 + 1] = v.y;
    }
    __syncthreads();
    #pragma unroll
    for (int r = 0; r < 32; ++r)
        out[(b0 + r) * 256 + tid] = tile[r][tid];
}

extern "C" void kernel_launch(void* const* d_in, const int* in_sizes, int n_in,
                              void* d_out, int out_size, void* d_ws, size_t ws_size,
                              hipStream_t stream)
{
    const float* x  = (const float*)d_in[0];
    const float* w0 = (const float*)d_in[1];
    const float* b0 = (const float*)d_in[2];
    const float* w1 = (const float*)d_in[3];
    const float* b1 = (const float*)d_in[4];
    const float* w2 = (const float*)d_in[5];
    const float* b2 = (const float*)d_in[6];
    float* out = (float*)d_out;

    const size_t OFF_W0  = 2359296;            // xp : 8192*144*2
    const size_t OFF_W1  = OFF_W0 + 2359296;   // w0p: 128*64*144*2
    const size_t OFF_W2  = OFF_W1 + 1310720;   // w1p: 128*64*80*2
    const size_t OFF_TMP = OFF_W2 + 655360;    // w2p: 128*32*80*2  -> 6684672
    const size_t NEED_TMP = OFF_TMP + 8388608; // + tmp 128*8192*2*4

    if (ws_size < OFF_TMP) return;

    char* ws = (char*)d_ws;
    __hip_bfloat16* xp  = (__hip_bfloat16*)(ws);
    __hip_bfloat16* w0p = (__hip_bfloat16*)(ws + OFF_W0);
    __hip_bfloat16* w1p = (__hip_bfloat16*)(ws + OFF_W1);
    __hip_bfloat16* w2p = (__hip_bfloat16*)(ws + OFF_W2);
    float* tmp = (float*)(ws + OFF_TMP);

    const int use_tmp = (ws_size >= NEED_TMP) ? 1 : 0;
    float* dstp = use_tmp ? tmp : out;

    prep_kernel<<<1632, 256, 0, stream>>>(x, w0, b0, w1, b1, w2, b2, xp, w0p, w1p, w2p);
    mlp_kernel<<<1024, 256, 0, stream>>>(xp, w0p, w1p, w2p, dstp, use_tmp ? 0 : 1);
    if (use_tmp)
        transpose_kernel<<<256, 256, 0, stream>>>(tmp, out);
}

// Round 7
// 120.222 us; speedup vs baseline: 1.6785x; 1.0761x over previous
//
#include <hip/hip_runtime.h>
#include <hip/hip_bf16.h>

typedef __attribute__((ext_vector_type(8))) short short8;
typedef __attribute__((ext_vector_type(16))) float f32x16;
typedef __attribute__((ext_vector_type(2))) unsigned uint2v;

#define LEAK 0.01f

__device__ __forceinline__ f32x16 mfma32(short8 a, short8 b, f32x16 c) {
    return __builtin_amdgcn_mfma_f32_32x32x16_bf16(a, b, c, 0, 0, 0);
}
__device__ __forceinline__ unsigned pkbf(float a, float b) {
    __hip_bfloat162 t = __float22bfloat162_rn(make_float2(a, b));
    return *reinterpret_cast<unsigned*>(&t);
}

// Half-wave swap. Target semantics (proven correct in round 5):
//   a' = [a@lanes<32, b@partner(lane-32)] ; b' = [a@partner(lane+32), b@lanes>=32]
// i.e. a' = [a_lo, b_lo], b' = [a_hi, b_hi].
#if defined(__has_builtin) && __has_builtin(__builtin_amdgcn_permlane32_swap)
__device__ __forceinline__ void plswap(unsigned &a, unsigned &b, int /*h*/) {
    uint2v r = __builtin_amdgcn_permlane32_swap(a, b, false, false);
    a = r.x; b = r.y;
}
#else
__device__ __forceinline__ void plswap(unsigned &a, unsigned &b, int h) {
    unsigned ax = (unsigned)__shfl_xor((int)a, 32);
    unsigned bx = (unsigned)__shfl_xor((int)b, 32);
    unsigned na = h ? bx : a;
    unsigned nb = h ? b  : ax;
    a = na; b = nb;
}
#endif

// Layer transition, fully in-register: acc (2x f32x16, D-layout rows
// (q&3)+8*(q>>2)+4h + 32nt, col=batch) -> 4 B-frags (k=16ks+8h+{0..7}),
// with leaky ReLU. pk[nt][s] = rows n0,n0+1, n0 = 32nt+8*(s>>1)+2*(s&1)+4h.
// dword d of out[ks] needs rows 16ks+8h+2d,+1  ->  s=4(ks&1)+2h+(d&1), h'=d>>1.
__device__ __forceinline__ void transition(const f32x16 &A0, const f32x16 &A1,
                                           short8 out[4], int h) {
    unsigned pk[2][8];
    #pragma unroll
    for (int nt = 0; nt < 2; ++nt) {
        const f32x16 &A = nt ? A1 : A0;
        #pragma unroll
        for (int s = 0; s < 8; ++s) {
            float u = A[2*s], v = A[2*s+1];
            u = fmaxf(u, LEAK * u); v = fmaxf(v, LEAK * v);
            pk[nt][s] = pkbf(u, v);
        }
    }
    #pragma unroll
    for (int ks = 0; ks < 4; ++ks) {
        const int nt = ks >> 1, ss = (ks & 1) * 4;
        unsigned d0 = pk[nt][ss], d1 = pk[nt][ss+1], d2 = pk[nt][ss+2], d3 = pk[nt][ss+3];
        plswap(d0, d2, h);   // d0 = dword0, d2 = dword2
        plswap(d1, d3, h);   // d1 = dword1, d3 = dword3
        union { unsigned u[4]; short8 s; } U;
        U.u[0] = d0; U.u[1] = d1; U.u[2] = d2; U.u[3] = d3;
        out[ks] = U.s;
    }
}

// ---------------- prep: bf16 + diag-mask + bias K-padding ----------------
// xp [8192][144]: k<128 = x, k==128 = 1, else 0
// w0p[128][64][144]: k<128 = w0 (j==t zeroed), k==128 = b0, else 0
// w1p[128][64][80]:  k<64 = w1, k==64 = b1, else 0
// w2p[128][32][80]:  n<2: k<64 = w2, k==64 = b2; else 0
__global__ __launch_bounds__(256) void prep_kernel(
    const float* __restrict__ x,  const float* __restrict__ w0, const float* __restrict__ b0,
    const float* __restrict__ w1, const float* __restrict__ b1,
    const float* __restrict__ w2, const float* __restrict__ b2,
    __hip_bfloat16* __restrict__ xp,  __hip_bfloat16* __restrict__ w0p,
    __hip_bfloat16* __restrict__ w1p, __hip_bfloat16* __restrict__ w2p)
{
    const int idx = blockIdx.x * 256 + threadIdx.x;
    float v[8];
    #pragma unroll
    for (int e = 0; e < 8; ++e) v[e] = 0.f;
    __hip_bfloat16* dst;

    if (idx < 147456) {                       // xp
        int b = idx / 18, ch = idx - b * 18;
        dst = xp + b * 144 + ch * 8;
        if (ch < 16) {
            const float* s = x + b * 128 + ch * 8;
            #pragma unroll
            for (int e = 0; e < 8; ++e) v[e] = s[e];
        } else if (ch == 16) v[0] = 1.f;
    } else if (idx < 294912) {                // w0p
        int i = idx - 147456;
        int r = i / 18, ch = i - r * 18;      // r = t*64+n
        int t = r >> 6;
        dst = w0p + r * 144 + ch * 8;
        if (ch < 16) {
            const float* s = w0 + r * 128 + ch * 8;
            #pragma unroll
            for (int e = 0; e < 8; ++e) v[e] = s[e];
            if ((t >> 3) == ch) v[t & 7] = 0.f;   // mask j == t
        } else if (ch == 16) v[0] = b0[r];
    } else if (idx < 376832) {                // w1p
        int i = idx - 294912;
        int r = i / 10, ch = i - r * 10;
        dst = w1p + r * 80 + ch * 8;
        if (ch < 8) {
            const float* s = w1 + r * 64 + ch * 8;
            #pragma unroll
            for (int e = 0; e < 8; ++e) v[e] = s[e];
        } else if (ch == 8) v[0] = b1[r];
    } else {                                  // w2p
        int i = idx - 376832;
        int r = i / 10, ch = i - r * 10;      // r = t*32+n
        int t = r >> 5, n = r & 31;
        dst = w2p + r * 80 + ch * 8;
        if (n < 2) {
            if (ch < 8) {
                const float* s = w2 + (t * 2 + n) * 64 + ch * 8;
                #pragma unroll
                for (int e = 0; e < 8; ++e) v[e] = s[e];
            } else if (ch == 8) v[0] = b2[t * 2 + n];
        }
    }
    union { unsigned u[4]; short8 s; } U;
    #pragma unroll
    for (int p = 0; p < 4; ++p) U.u[p] = pkbf(v[2*p], v[2*p+1]);
    *reinterpret_cast<short8*>(dst) = U.s;
}

// ---------------- main fused MLP: 32x32 MFMA + permlane transitions ----------------
// grid 1024 x 256. block -> (t, 1024 rows); wave -> 256 rows = 8 tiles of 32.
__global__ __launch_bounds__(256, 2) void mlp_kernel(
    const __hip_bfloat16* __restrict__ xp,
    const __hip_bfloat16* __restrict__ w0p,
    const __hip_bfloat16* __restrict__ w1p,
    const __hip_bfloat16* __restrict__ w2p,
    float* __restrict__ dst, int direct)
{
    const int tid  = threadIdx.x;
    const int wave = tid >> 6;
    const int lane = tid & 63;
    const int h    = lane >> 5;
    const int c    = lane & 31;

    const int bid   = blockIdx.x;
    const int t     = (bid & 7) * 16 + ((bid >> 3) & 15);  // XCD k owns t in [16k,16k+16)
    const int chunk = bid >> 7;                            // 0..7
    const int rb0   = chunk * 1024 + wave * 256;

    // ---- x B-frags for tile 0 (issue first: on the critical path) ----
    const __hip_bfloat16* xr0 = xp + (rb0 + c) * 144 + h * 8;
    short8 xf[9];
    #pragma unroll
    for (int ks = 0; ks < 9; ++ks)
        xf[ks] = *reinterpret_cast<const short8*>(xr0 + ks * 16);

    // ---- weight A-fragments, register-resident (A[n][k]: n=32nt+c, k=16ks+8h+e) ----
    const __hip_bfloat16* w0t = w0p + t * 9216;
    const __hip_bfloat16* w1t = w1p + t * 5120;
    const __hip_bfloat16* w2t = w2p + t * 2560;
    short8 w0f[2][9], w1f[2][5], w2f[5];
    #pragma unroll
    for (int nt = 0; nt < 2; ++nt)
        #pragma unroll
        for (int ks = 0; ks < 9; ++ks)
            w0f[nt][ks] = *reinterpret_cast<const short8*>(w0t + (nt*32 + c)*144 + ks*16 + h*8);
    #pragma unroll
    for (int nt = 0; nt < 2; ++nt)
        #pragma unroll
        for (int ks = 0; ks < 5; ++ks)
            w1f[nt][ks] = *reinterpret_cast<const short8*>(w1t + (nt*32 + c)*80 + ks*16 + h*8);
    #pragma unroll
    for (int ks = 0; ks < 5; ++ks)
        w2f[ks] = *reinterpret_cast<const short8*>(w2t + c*80 + ks*16 + h*8);

    // constant B-frag for the bias row (k=64 -> 1.0): h==0, e==0 slot
    union { unsigned u[4]; short8 s; } OneU;
    OneU.u[0] = (h == 0) ? 0x00003f80u : 0u;
    OneU.u[1] = 0u; OneU.u[2] = 0u; OneU.u[3] = 0u;
    const short8 onef = OneU.s;

    #pragma unroll 2
    for (int tile = 0; tile < 8; ++tile) {
        const int brow = rb0 + tile * 32 + c;

        // ---- prefetch next tile's x B-frags (latency hides under 3 layers) ----
        short8 xn[9];
        if (tile < 7) {
            const __hip_bfloat16* xr = xr0 + (tile + 1) * (32 * 144);
            #pragma unroll
            for (int ks = 0; ks < 9; ++ks)
                xn[ks] = *reinterpret_cast<const short8*>(xr + ks * 16);
        }

        // ---- layer 0: 18 MFMA (bias via K-pad col 128) ----
        f32x16 acc0a, acc0b;
        #pragma unroll
        for (int i = 0; i < 16; ++i) { acc0a[i] = 0.f; acc0b[i] = 0.f; }
        __builtin_amdgcn_s_setprio(1);
        #pragma unroll
        for (int ks = 0; ks < 9; ++ks) {
            acc0a = mfma32(w0f[0][ks], xf[ks], acc0a);
            acc0b = mfma32(w0f[1][ks], xf[ks], acc0b);
        }
        __builtin_amdgcn_s_setprio(0);

        short8 h1f[4];
        transition(acc0a, acc0b, h1f, h);

        // ---- layer 1: 10 MFMA (bias row via onef) ----
        f32x16 acc1a, acc1b;
        #pragma unroll
        for (int i = 0; i < 16; ++i) { acc1a[i] = 0.f; acc1b[i] = 0.f; }
        __builtin_amdgcn_s_setprio(1);
        #pragma unroll
        for (int ks = 0; ks < 4; ++ks) {
            acc1a = mfma32(w1f[0][ks], h1f[ks], acc1a);
            acc1b = mfma32(w1f[1][ks], h1f[ks], acc1b);
        }
        acc1a = mfma32(w1f[0][4], onef, acc1a);
        acc1b = mfma32(w1f[1][4], onef, acc1b);
        __builtin_amdgcn_s_setprio(0);

        short8 h2f[4];
        transition(acc1a, acc1b, h2f, h);

        // ---- layer 2: 5 MFMA (rows 0,1 real) ----
        f32x16 acc2;
        #pragma unroll
        for (int i = 0; i < 16; ++i) acc2[i] = 0.f;
        __builtin_amdgcn_s_setprio(1);
        #pragma unroll
        for (int ks = 0; ks < 4; ++ks) acc2 = mfma32(w2f[ks], h2f[ks], acc2);
        acc2 = mfma32(w2f[4], onef, acc2);
        __builtin_amdgcn_s_setprio(0);

        // ---- store: lanes h==0 hold out[p=0][b]=reg0, out[p=1][b]=reg1 ----
        if (h == 0) {
            float2 v = make_float2(acc2[0], acc2[1]);
            if (direct) *reinterpret_cast<float2*>(dst + brow * 256 + t * 2) = v;
            else        *reinterpret_cast<float2*>(dst + t * 16384 + brow * 2) = v;
        }

        #pragma unroll
        for (int ks = 0; ks < 9; ++ks) xf[ks] = xn[ks];
    }
}

// ---------------- transpose: tmp[128][8192][2] f32 -> out[8192][256] ----------------
__global__ __launch_bounds__(256) void transpose_kernel(
    const float* __restrict__ tmp, float* __restrict__ out)
{
    __shared__ float tile[32][257];
    const int b0 = blockIdx.x * 32;
    const int tid = threadIdx.x;
    #pragma unroll
    for (int it = 0; it < 16; ++it) {
        int idx = it * 256 + tid;
        int tt = idx >> 5, r = idx & 31;
        float2 v = *reinterpret_cast<const float2*>(tmp + tt * 16384 + (b0 + r) * 2);
        tile[r][tt * 2]     = v.x;
        tile[r][tt * 2 + 1] = v.y;
    }
    __syncthreads();
    #pragma unroll
    for (int r = 0; r < 32; ++r)
        out[(b0 + r) * 256 + tid] = tile[r][tid];
}

extern "C" void kernel_launch(void* const* d_in, const int* in_sizes, int n_in,
                              void* d_out, int out_size, void* d_ws, size_t ws_size,
                              hipStream_t stream)
{
    const float* x  = (const float*)d_in[0];
    const float* w0 = (const float*)d_in[1];
    const float* b0 = (const float*)d_in[2];
    const float* w1 = (const float*)d_in[3];
    const float* b1 = (const float*)d_in[4];
    const float* w2 = (const float*)d_in[5];
    const float* b2 = (const float*)d_in[6];
    float* out = (float*)d_out;

    const size_t OFF_W0  = 2359296;            // xp : 8192*144*2
    const size_t OFF_W1  = OFF_W0 + 2359296;   // w0p: 128*64*144*2
    const size_t OFF_W2  = OFF_W1 + 1310720;   // w1p: 128*64*80*2
    const size_t OFF_TMP = OFF_W2 + 655360;    // w2p: 128*32*80*2  -> 6684672
    const size_t NEED_TMP = OFF_TMP + 8388608; // + tmp 128*8192*2*4

    if (ws_size < OFF_TMP) return;

    char* ws = (char*)d_ws;
    __hip_bfloat16* xp  = (__hip_bfloat16*)(ws);
    __hip_bfloat16* w0p = (__hip_bfloat16*)(ws + OFF_W0);
    __hip_bfloat16* w1p = (__hip_bfloat16*)(ws + OFF_W1);
    __hip_bfloat16* w2p = (__hip_bfloat16*)(ws + OFF_W2);
    float* tmp = (float*)(ws + OFF_TMP);

    const int use_tmp = (ws_size >= NEED_TMP) ? 1 : 0;
    float* dstp = use_tmp ? tmp : out;

    prep_kernel<<<1632, 256, 0, stream>>>(x, w0, b0, w1, b1, w2, b2, xp, w0p, w1p, w2p);
    mlp_kernel<<<1024, 256, 0, stream>>>(xp, w0p, w1p, w2p, dstp, use_tmp ? 0 : 1);
    if (use_tmp)
        transpose_kernel<<<256, 256, 0, stream>>>(tmp, out);
}